// Round 18
// baseline (225.395 us; speedup 1.0000x reference)
//
#include <hip/hip_runtime.h>
#include <hip/hip_bf16.h>
#include <cstdint>
#include <cstddef>

typedef __bf16 bf16;
typedef __attribute__((ext_vector_type(8))) __bf16 bf16x8;
typedef __attribute__((ext_vector_type(4))) __bf16 bf16x4;
typedef __attribute__((ext_vector_type(4))) float f32x4;
typedef __attribute__((ext_vector_type(4))) int i32x4;

#define MFMA_BF16(a, b, c) __builtin_amdgcn_mfma_f32_16x16x32_bf16((a), (b), (c), 0, 0, 0)

constexpr int CB = 4;       // batch
constexpr int CS = 2048;    // seq
constexpr int CD = 1024;    // model dim
constexpr int CDA = 1024;   // attn dim
constexpr int CH = 16;      // heads
constexpr int CM = CB * CS; // 8192 rows
constexpr int NT = CS / 64; // 32 key tiles

// ---------------------------------------------------------------------------
// Weight pre-convert: 4 x [1024x1024] fp32 -> bf16 (linear layout).
// ---------------------------------------------------------------------------
__global__ __launch_bounds__(256) void cvt_w4(
    const float* __restrict__ s0, const float* __restrict__ s1,
    const float* __restrict__ s2, const float* __restrict__ s3,
    bf16* __restrict__ dst)
{
    int bid = blockIdx.x;
    int m = bid >> 9;                                 // 512 blocks per matrix
    size_t li = ((size_t)(bid & 511) * 256 + threadIdx.x) * 8;
    const float* s = (m == 0) ? s0 : (m == 1) ? s1 : (m == 2) ? s2 : s3;
    f32x4 a = *(const f32x4*)(s + li);
    f32x4 c = *(const f32x4*)(s + li + 4);
    bf16x8 o;
#pragma unroll
    for (int j = 0; j < 4; ++j) { o[j] = (bf16)a[j]; o[4 + j] = (bf16)c[j]; }
    *(bf16x8*)(dst + (size_t)m * (CD * CDA) + li) = o;
}

// ---------------------------------------------------------------------------
// Fused Q/K/V projection GEMM. BM=128 x BN=256 x *** BK=128 ***, 512 thr.
// Rationale: proj sits at MfmaUtil 17.7 / VALU 11.8 -> time is dominated by
// per-K-step fixed overhead (stage + drain + 2 barriers; m233-class stall).
// BK 64->128 HALVES the barrier-event count (8 K-steps, 64 MFMA per pair)
// at unchanged occupancy (single 96K buffer, 1 block/CU, same as r13's 96K).
// LDS: A 32K (row stride 256B) + B 64K. Swizzle: 16B slot s holds K-block
// s^(row&7) -> same conflict-free mod-128 structure as the measured-zero
// BK=64 layout (row stride 256B = 2 bank-cycles drops out of bank math).
// z==2 writes xvT (C^T with within-64 cp() permutation on M).
// ---------------------------------------------------------------------------
struct P3 {
    const float *A0, *A1, *A2;
    const float *b0, *b1, *b2;
    bf16 *C0, *C1, *C2;
};

__global__ __launch_bounds__(512, 2) void gemm_proj(P3 p, const bf16* __restrict__ Wb)
{
    __shared__ __align__(16) char smem[98304];  // A 32K @0, B 64K @32768

    const int t = threadIdx.x;
    const int lane = t & 63;
    const int wid = t >> 6;
    const int wr = wid >> 2, wc = wid & 3;
    const int l15 = lane & 15, lg = lane >> 4;
    const int m0 = blockIdx.x * 128;
    const int n0 = blockIdx.y * 256;
    const int z = blockIdx.z;

    const float* A    = (z == 0) ? p.A0 : (z == 1) ? p.A1 : p.A2;
    const float* bias = (z == 0) ? p.b0 : (z == 1) ? p.b1 : p.b2;
    const bf16*  W    = Wb + (size_t)z * (CD * CDA);

    // A staging: 4 threads per row; thread covers 32 fp32 cols = 4 slots
    const int arow = t >> 2, aq = t & 3;
    const float* asrc = A + (size_t)(m0 + arow) * CD + aq * 32;
    int aoff[4];
#pragma unroll
    for (int j = 0; j < 4; ++j)
        aoff[j] = arow * 256 + (((aq * 4 + j) ^ (arow & 7)) << 4);

    // B glds: 8 chunks of 16B/thread; chunk i covers rows i*32+wid*4..+3.
    // lane (hi=lane>>4, lo=lane&15) -> row +hi, slot lo holds K-block
    // lo^(row&7); (row&7) = (wid&1)*4 + hi  (since i*32 % 8 == 0).
    const int bhi = lane >> 4;
    const size_t bsrcoff = (size_t)bhi * CD +
                           (((lane & 15) ^ ((wid & 1) * 4 + bhi)) << 3);

    char* Ab = smem;
    char* Bb = smem + 32768;

    f32x4 acc[4][4] = {};

    for (int ks = 0; ks < CD / 128; ++ks) {
        const int k0 = ks * 128;
        // ---- stage A 128x128 (fp32 -> bf16), 8 loads + 4 b128 writes ----
#pragma unroll
        for (int j = 0; j < 4; ++j) {
            f32x4 v0 = *(const f32x4*)(asrc + k0 + j * 8);
            f32x4 v1 = *(const f32x4*)(asrc + k0 + j * 8 + 4);
            bf16x8 o;
#pragma unroll
            for (int jj = 0; jj < 4; ++jj) { o[jj] = (bf16)v0[jj]; o[4 + jj] = (bf16)v1[jj]; }
            *(bf16x8*)(Ab + aoff[j]) = o;
        }
        // ---- stage B 256x128 via glds (8 chunks/thread) ----
#pragma unroll
        for (int i = 0; i < 8; ++i) {
            const bf16* src = W + (size_t)(n0 + i * 32 + wid * 4) * CD + k0 + bsrcoff;
            __builtin_amdgcn_global_load_lds(
                (const __attribute__((address_space(1))) void*)src,
                (__attribute__((address_space(3))) void*)(Bb + i * 8192 + wid * 1024),
                16, 0, 0);
        }
        __syncthreads();  // stage visible (drains glds + A ds_writes)

#pragma unroll
        for (int kk = 0; kk < 128; kk += 32) {
            bf16x8 af[4], bfv[4];
#pragma unroll
            for (int mi = 0; mi < 4; ++mi) {
                int row = wr * 64 + mi * 16 + l15;
                af[mi] = *(const bf16x8*)(Ab + row * 256 +
                                          ((((kk >> 3) + lg) ^ (row & 7)) << 4));
            }
#pragma unroll
            for (int ni = 0; ni < 4; ++ni) {
                int row = wc * 64 + ni * 16 + l15;
                bfv[ni] = *(const bf16x8*)(Bb + row * 256 +
                                           ((((kk >> 3) + lg) ^ (row & 7)) << 4));
            }
            __builtin_amdgcn_s_setprio(1);
#pragma unroll
            for (int mi = 0; mi < 4; ++mi)
#pragma unroll
                for (int ni = 0; ni < 4; ++ni)
                    acc[mi][ni] = MFMA_BF16(af[mi], bfv[ni], acc[mi][ni]);
            __builtin_amdgcn_s_setprio(0);
        }
        __syncthreads();  // compute done before next stage overwrites
    }

    if (z == 2) {
        // xvT: (m,n) -> C2[n*CM + (m&~63) | cp(m&63)]
        bf16* C = p.C2;
        const int mblock = m0 + wr * 64;
#pragma unroll
        for (int ni = 0; ni < 4; ++ni) {
            int n = n0 + wc * 64 + ni * 16 + l15;
            float bv = bias[n];
#pragma unroll
            for (int mi = 0; mi < 4; ++mi) {
                int s = mi * 16 + lg * 4;  // s&3 == 0
                int cps = (s & 32) | ((s & 12) << 1) | ((s & 16) >> 2);
                bf16x4 o;
#pragma unroll
                for (int r = 0; r < 4; ++r) o[r] = (bf16)(acc[mi][ni][r] + bv);
                *(bf16x4*)(C + (size_t)n * CM + mblock + cps) = o;
            }
        }
    } else {
        bf16* C = (z == 0) ? p.C0 : p.C1;
#pragma unroll
        for (int ni = 0; ni < 4; ++ni) {
            int col = n0 + wc * 64 + ni * 16 + l15;
            float bv = bias[col];
#pragma unroll
            for (int mi = 0; mi < 4; ++mi)
#pragma unroll
                for (int r = 0; r < 4; ++r) {
                    int row = m0 + wr * 64 + mi * 16 + lg * 4 + r;
                    C[(size_t)row * CDA + col] = (bf16)(acc[mi][ni][r] + bv);
                }
        }
    }
}

// ---------------------------------------------------------------------------
// Output projection (unchanged from r13: dbuf glds pipeline, 1 blk/CU).
// ---------------------------------------------------------------------------
__global__ __launch_bounds__(512, 2) void gemm_out(
    const bf16* __restrict__ A, const bf16* __restrict__ W,
    const float* __restrict__ bias, float* __restrict__ C)
{
    __shared__ __align__(16) char smem[98304];  // A: 2x16K @0, B: 2x32K @32768

    const int t = threadIdx.x;
    const int lane = t & 63;
    const int wid = t >> 6;
    const int wr = wid >> 2, wc = wid & 3;
    const int l15 = lane & 15, lg = lane >> 4;
    const int m0 = blockIdx.x * 128;
    const int n0 = blockIdx.y * 256;

    const int grow_ = wid * 8 + (lane >> 3);
    const int gcol = ((lane & 7) ^ ((lane >> 3) & 7)) << 3;

    auto STAGE = [&](int bufi, int k0) {
        char* Ab = smem + bufi * 16384;
        char* Bb = smem + 32768 + bufi * 32768;
#pragma unroll
        for (int i = 0; i < 2; ++i) {
            const bf16* src = A + (size_t)(m0 + i * 64 + grow_) * CDA + k0 + gcol;
            __builtin_amdgcn_global_load_lds(
                (const __attribute__((address_space(1))) void*)src,
                (__attribute__((address_space(3))) void*)(Ab + i * 8192 + wid * 1024),
                16, 0, 0);
        }
#pragma unroll
        for (int i = 0; i < 4; ++i) {
            const bf16* src = W + (size_t)(n0 + i * 64 + grow_) * CDA + k0 + gcol;
            __builtin_amdgcn_global_load_lds(
                (const __attribute__((address_space(1))) void*)src,
                (__attribute__((address_space(3))) void*)(Bb + i * 8192 + wid * 1024),
                16, 0, 0);
        }
    };

    f32x4 acc[4][4] = {};

    STAGE(0, 0);
    __syncthreads();

    for (int ks = 0; ks < CDA / 64; ++ks) {
        const int cur = ks & 1;
        if (ks + 1 < CDA / 64) STAGE(cur ^ 1, (ks + 1) * 64);
        char* Ab = smem + cur * 16384;
        char* Bb = smem + 32768 + cur * 32768;
#pragma unroll
        for (int kk = 0; kk < 64; kk += 32) {
            bf16x8 af[4], bfv[4];
#pragma unroll
            for (int mi = 0; mi < 4; ++mi) {
                int row = wr * 64 + mi * 16 + l15;
                af[mi] = *(const bf16x8*)(Ab + row * 128 +
                                          ((((kk >> 3) + lg) ^ (row & 7)) << 4));
            }
#pragma unroll
            for (int ni = 0; ni < 4; ++ni) {
                int row = wc * 64 + ni * 16 + l15;
                bfv[ni] = *(const bf16x8*)(Bb + 128 * row +
                                           ((((kk >> 3) + lg) ^ (row & 7)) << 4));
            }
            __builtin_amdgcn_s_setprio(1);
#pragma unroll
            for (int mi = 0; mi < 4; ++mi)
#pragma unroll
                for (int ni = 0; ni < 4; ++ni)
                    acc[mi][ni] = MFMA_BF16(af[mi], bfv[ni], acc[mi][ni]);
            __builtin_amdgcn_s_setprio(0);
        }
        __syncthreads();  // drains next-tile glds (covered by compute); buffer reuse
    }

#pragma unroll
    for (int ni = 0; ni < 4; ++ni) {
        int col = n0 + wc * 64 + ni * 16 + l15;
        float bv = bias[col];
#pragma unroll
        for (int mi = 0; mi < 4; ++mi)
#pragma unroll
            for (int r = 0; r < 4; ++r) {
                int row = m0 + wr * 64 + mi * 16 + lg * 4 + r;
                C[(size_t)row * CD + col] = acc[mi][ni][r] + bv;
            }
    }
}

// ---------------------------------------------------------------------------
// Flash attention — best-known version (2-buffer glds, __syncthreads drain).
// 512 threads = 8 waves, 256 q-rows/block, XCD-swizzled grid of 512.
// ---------------------------------------------------------------------------
__global__ __launch_bounds__(512, 4) void attn_kernel(
    const bf16* __restrict__ xq, const bf16* __restrict__ xk,
    const bf16* __restrict__ xvT, const int* __restrict__ mask,
    bf16* __restrict__ out)
{
    __shared__ __align__(16) char smem[40960];
    float* Mb = (float*)(smem + 32768);        // per-block mask bias, f32[2048]

    const int t = threadIdx.x;
    const int lane = t & 63;
    const int wid = t >> 6;                    // 0..7
    const int l15 = lane & 15, lg = lane >> 4;
    const int g = blockIdx.x;
    const int j = g >> 3;
    const int bh = (g & 7) * 8 + (j & 7);
    const int qt = j >> 3;
    const int b = bh >> 4, h = bh & 15;
    const int q0 = qt * 256;
    constexpr float SCL = 0.125f * 1.44269504088896340736f;
    constexpr float M2 = 12.0f * SCL;

    const int sub = lane >> 3;
    const int sb  = (lane & 7) ^ sub;
    const bf16* kbase = xk + (size_t)(b * CS + wid * 8 + sub) * CDA + h * 64 + sb * 8;
    const bf16* vbase = xvT + (size_t)(h * 64 + wid * 8 + sub) * CM + b * CS + sb * 8;

#define STAGE(bufi, ktt)                                                           \
    {                                                                              \
        char* Kd = smem + (bufi) * 16384 + wid * 1024;                             \
        char* Vd = smem + (bufi) * 16384 + 8192 + wid * 1024;                      \
        __builtin_amdgcn_global_load_lds(                                          \
            (const __attribute__((address_space(1))) void*)(kbase + (size_t)(ktt) * 64 * CDA), \
            (__attribute__((address_space(3))) void*)Kd, 16, 0, 0);                \
        __builtin_amdgcn_global_load_lds(                                          \
            (const __attribute__((address_space(1))) void*)(vbase + (ktt) * 64),   \
            (__attribute__((address_space(3))) void*)Vd, 16, 0, 0);                \
    }

    {
        i32x4 mk = *(const i32x4*)(mask + b * CS + t * 4);
        f32x4 o;
#pragma unroll
        for (int r = 0; r < 4; ++r) o[r] = (mk[r] == 0) ? -1.0e30f : -M2;
        *(f32x4*)(Mb + t * 4) = o;
    }

    bf16x8 aq[2][2];
#pragma unroll
    for (int mi = 0; mi < 2; ++mi)
#pragma unroll
        for (int kh = 0; kh < 2; ++kh) {
            bf16x8 v = *(const bf16x8*)(xq +
                (size_t)(b * CS + q0 + wid * 32 + mi * 16 + l15) * CDA + h * 64 + kh * 32 + lg * 8);
#pragma unroll
            for (int jj = 0; jj < 8; ++jj) v[jj] = (bf16)((float)v[jj] * SCL);
            aq[mi][kh] = v;
        }

    bf16x8 onescol;
    {
        bf16 fv = (l15 == 0) ? (bf16)1.0f : (bf16)0.0f;
#pragma unroll
        for (int jj = 0; jj < 8; ++jj) onescol[jj] = fv;
    }

    int koff[2][4], voff[2][4];
#pragma unroll
    for (int kh = 0; kh < 2; ++kh)
#pragma unroll
        for (int ni = 0; ni < 4; ++ni) {
            int key = ni * 16 + l15;
            koff[kh][ni] = key * 128 + ((kh * 64 + lg * 16) ^ ((key & 7) << 4));
        }
#pragma unroll
    for (int kks = 0; kks < 2; ++kks)
#pragma unroll
        for (int di = 0; di < 4; ++di) {
            int d = di * 16 + l15;
            voff[kks][di] = 8192 + d * 128 + ((kks * 64 + lg * 16) ^ ((d & 7) << 4));
        }

    f32x4 accO[2][5] = {};

    STAGE(0, 0);
    __syncthreads();

    for (int kt = 0; kt < NT; ++kt) {
        const int cur = kt & 1;
        char* buf = smem + cur * 16384;

        if (kt + 1 < NT) STAGE(cur ^ 1, kt + 1);

        f32x4 mb[4];
#pragma unroll
        for (int ni = 0; ni < 4; ++ni)
            mb[ni] = *(const f32x4*)(Mb + kt * 64 + ni * 16 + lg * 4);

        f32x4 sT[4][2];
#pragma unroll
        for (int ni = 0; ni < 4; ++ni) { sT[ni][0] = mb[ni]; sT[ni][1] = mb[ni]; }
#pragma unroll
        for (int kh = 0; kh < 2; ++kh) {
            bf16x8 bk[4];
#pragma unroll
            for (int ni = 0; ni < 4; ++ni)
                bk[ni] = *(const bf16x8*)(buf + koff[kh][ni]);
            __builtin_amdgcn_s_setprio(1);
#pragma unroll
            for (int ni = 0; ni < 4; ++ni)
#pragma unroll
                for (int mi = 0; mi < 2; ++mi)
                    sT[ni][mi] = MFMA_BF16(bk[ni], aq[mi][kh], sT[ni][mi]);
            __builtin_amdgcn_s_setprio(0);
        }

#pragma unroll
        for (int ni = 0; ni < 4; ++ni)
#pragma unroll
            for (int mi = 0; mi < 2; ++mi)
#pragma unroll
                for (int r = 0; r < 4; ++r)
                    sT[ni][mi][r] = exp2f(sT[ni][mi][r]);

        bf16x8 ap[2][2];
#pragma unroll
        for (int kks = 0; kks < 2; ++kks)
#pragma unroll
            for (int mi = 0; mi < 2; ++mi)
#pragma unroll
                for (int r = 0; r < 4; ++r) {
                    ap[kks][mi][r]     = (bf16)sT[2 * kks][mi][r];
                    ap[kks][mi][4 + r] = (bf16)sT[2 * kks + 1][mi][r];
                }

#pragma unroll
        for (int kks = 0; kks < 2; ++kks) {
            bf16x8 bv[4];
#pragma unroll
            for (int di = 0; di < 4; ++di)
                bv[di] = *(const bf16x8*)(buf + voff[kks][di]);
            __builtin_amdgcn_s_setprio(1);
#pragma unroll
            for (int mi = 0; mi < 2; ++mi) {
#pragma unroll
                for (int di = 0; di < 4; ++di)
                    accO[mi][di] = MFMA_BF16(ap[kks][mi], bv[di], accO[mi][di]);
                accO[mi][4] = MFMA_BF16(ap[kks][mi], onescol, accO[mi][4]);
            }
            __builtin_amdgcn_s_setprio(0);
        }

        __syncthreads();
    }
#undef STAGE

    char* Ob = smem + wid * 2048;
#pragma unroll
    for (int mi = 0; mi < 2; ++mi) {
#pragma unroll
        for (int r = 0; r < 4; ++r) {
            float lsum = __shfl(accO[mi][4][r], lane & 48);
            float inv = 1.0f / lsum;
            int qr = lg * 4 + r;
#pragma unroll
            for (int di = 0; di < 4; ++di)
                *(bf16*)(Ob + qr * 128 + (((di * 16 + l15) * 2) ^ ((qr & 7) << 4))) =
                    (bf16)(accO[mi][di][r] * inv);
        }
        __builtin_amdgcn_sched_barrier(0);
#pragma unroll
        for (int i = 0; i < 2; ++i) {
            int rr = i * 8 + (lane >> 3);
            int ch = lane & 7;
            bf16x8 o = *(const bf16x8*)(Ob + rr * 128 + ((ch * 16) ^ ((rr & 7) << 4)));
            *(bf16x8*)(out + (size_t)(b * CS + q0 + wid * 32 + mi * 16 + rr) * CDA +
                       h * 64 + ch * 8) = o;
        }
        __builtin_amdgcn_sched_barrier(0);
    }
}

// ---------------------------------------------------------------------------
extern "C" void kernel_launch(void* const* d_in, const int* in_sizes, int n_in,
                              void* d_out, int out_size, void* d_ws, size_t ws_size,
                              hipStream_t stream)
{
    const float* q   = (const float*)d_in[0];
    const float* k   = (const float*)d_in[1];
    const float* v   = (const float*)d_in[2];
    const int*   msk = (const int*)d_in[3];
    const float* w_q = (const float*)d_in[4];
    const float* b_q = (const float*)d_in[5];
    const float* w_k = (const float*)d_in[6];
    const float* b_k = (const float*)d_in[7];
    const float* w_v = (const float*)d_in[8];
    const float* b_v = (const float*)d_in[9];
    const float* w_o = (const float*)d_in[10];
    const float* b_o = (const float*)d_in[11];

    bf16* xq  = (bf16*)d_ws;
    bf16* xk  = xq + (size_t)CM * CDA;
    bf16* xvT = xk + (size_t)CM * CDA;   // [DA][CM], keys permuted within 64-blocks
    bf16* at  = xvT + (size_t)CM * CDA;
    bf16* wb  = at + (size_t)CM * CDA;   // 4 x 1M bf16 weights (q,k,v,o)

    cvt_w4<<<dim3(2048), 256, 0, stream>>>(w_q, w_k, w_v, w_o, wb);

    P3 p{q, k, v, b_q, b_k, b_v, xq, xk, xvT};
    gemm_proj<<<dim3(CM / 128, CDA / 256, 3), 512, 0, stream>>>(p, wb);

    attn_kernel<<<dim3(512), 512, 0, stream>>>(xq, xk, xvT, msk, at);

    gemm_out<<<dim3(CM / 128, CD / 256), 512, 0, stream>>>(
        at, wb + 3 * (size_t)(CD * CDA), b_o, (float*)d_out);
}

// Round 19
// 193.952 us; speedup vs baseline: 1.1621x; 1.1621x over previous
//
#include <hip/hip_runtime.h>
#include <hip/hip_bf16.h>
#include <cstdint>
#include <cstddef>

typedef __bf16 bf16;
typedef __attribute__((ext_vector_type(8))) __bf16 bf16x8;
typedef __attribute__((ext_vector_type(4))) __bf16 bf16x4;
typedef __attribute__((ext_vector_type(4))) float f32x4;
typedef __attribute__((ext_vector_type(4))) int i32x4;

#define MFMA_BF16(a, b, c) __builtin_amdgcn_mfma_f32_16x16x32_bf16((a), (b), (c), 0, 0, 0)

constexpr int CB = 4;       // batch
constexpr int CS = 2048;    // seq
constexpr int CD = 1024;    // model dim
constexpr int CDA = 1024;   // attn dim
constexpr int CH = 16;      // heads
constexpr int CM = CB * CS; // 8192 rows
constexpr int NT = CS / 64; // 32 key tiles

// ---------------------------------------------------------------------------
// Weight pre-convert: 4 x [1024x1024] fp32 -> bf16 (linear layout).
// ---------------------------------------------------------------------------
__global__ __launch_bounds__(256) void cvt_w4(
    const float* __restrict__ s0, const float* __restrict__ s1,
    const float* __restrict__ s2, const float* __restrict__ s3,
    bf16* __restrict__ dst)
{
    int bid = blockIdx.x;
    int m = bid >> 9;                                 // 512 blocks per matrix
    size_t li = ((size_t)(bid & 511) * 256 + threadIdx.x) * 8;
    const float* s = (m == 0) ? s0 : (m == 1) ? s1 : (m == 2) ? s2 : s3;
    f32x4 a = *(const f32x4*)(s + li);
    f32x4 c = *(const f32x4*)(s + li + 4);
    bf16x8 o;
#pragma unroll
    for (int j = 0; j < 4; ++j) { o[j] = (bf16)a[j]; o[4 + j] = (bf16)c[j]; }
    *(bf16x8*)(dst + (size_t)m * (CD * CDA) + li) = o;
}

// ---------------------------------------------------------------------------
// Fused Q/K/V projection GEMM. BM=128 x BN=256 x BK=64, 512 thr = 8 waves.
// ONE barrier per K-step, all latency covered (T14 split):
//   iter k: {issue B-glds(k+1) -> Bb[cur^1]; issue A f32-loads(k+1) -> regs;
//            compute(k); cvt+ds_write A(k+1) -> Ab[cur^1]; barrier}
// LDS 96K (A 2x16K + B 2x32K) -> 1 block/CU; launch_bounds(512,2): no spill.
// z==2 writes xvT (C^T with within-64 cp() permutation on M).
// ---------------------------------------------------------------------------
struct P3 {
    const float *A0, *A1, *A2;
    const float *b0, *b1, *b2;
    bf16 *C0, *C1, *C2;
};

__global__ __launch_bounds__(512, 2) void gemm_proj(P3 p, const bf16* __restrict__ Wb)
{
    __shared__ __align__(16) char smem[98304];  // A: 2x16K @0, B: 2x32K @32768

    const int t = threadIdx.x;
    const int lane = t & 63;
    const int wid = t >> 6;
    const int wr = wid >> 2, wc = wid & 3;
    const int l15 = lane & 15, lg = lane >> 4;
    const int m0 = blockIdx.x * 128;
    const int n0 = blockIdx.y * 256;
    const int z = blockIdx.z;

    const float* A    = (z == 0) ? p.A0 : (z == 1) ? p.A1 : p.A2;
    const float* bias = (z == 0) ? p.b0 : (z == 1) ? p.b1 : p.b2;
    const bf16*  W    = Wb + (size_t)z * (CD * CDA);

    const int arow = t >> 2, aq = t & 3;
    const float* asrc = A + (size_t)(m0 + arow) * CD + aq * 16;
    const int aoff0 = arow * 128 + (((2 * aq) ^ (arow & 7)) << 4);
    const int aoff1 = arow * 128 + (((2 * aq + 1) ^ (arow & 7)) << 4);
    const int brow_ = wid * 8 + (lane >> 3);
    const int bcol = ((lane & 7) ^ ((lane >> 3) & 7)) << 3;

    f32x4 av0, av1, av2, av3;   // T14: A(k+1) in flight across compute(k)

    auto ALOAD = [&](int k0) {
        av0 = *(const f32x4*)(asrc + k0);
        av1 = *(const f32x4*)(asrc + k0 + 4);
        av2 = *(const f32x4*)(asrc + k0 + 8);
        av3 = *(const f32x4*)(asrc + k0 + 12);
    };
    auto AWRITE = [&](int bufi) {
        char* Ab = smem + bufi * 16384;
        bf16x8 o0, o1;
#pragma unroll
        for (int jj = 0; jj < 4; ++jj) {
            o0[jj] = (bf16)av0[jj]; o0[4 + jj] = (bf16)av1[jj];
            o1[jj] = (bf16)av2[jj]; o1[4 + jj] = (bf16)av3[jj];
        }
        *(bf16x8*)(Ab + aoff0) = o0;
        *(bf16x8*)(Ab + aoff1) = o1;
    };
    auto BSTAGE = [&](int bufi, int k0) {
        char* Bb = smem + 32768 + bufi * 32768;
#pragma unroll
        for (int i = 0; i < 4; ++i) {
            const bf16* src = W + (size_t)(n0 + i * 64 + brow_) * CD + k0 + bcol;
            __builtin_amdgcn_global_load_lds(
                (const __attribute__((address_space(1))) void*)src,
                (__attribute__((address_space(3))) void*)(Bb + i * 8192 + wid * 1024),
                16, 0, 0);
        }
    };

    f32x4 acc[4][4] = {};

    ALOAD(0); BSTAGE(0, 0); AWRITE(0);
    __syncthreads();

    for (int ks = 0; ks < CD / 64; ++ks) {
        const int cur = ks & 1;
        if (ks + 1 < CD / 64) { BSTAGE(cur ^ 1, (ks + 1) * 64); ALOAD((ks + 1) * 64); }
        char* Ab = smem + cur * 16384;
        char* Bb = smem + 32768 + cur * 32768;
#pragma unroll
        for (int kk = 0; kk < 64; kk += 32) {
            bf16x8 af[4], bfv[4];
#pragma unroll
            for (int mi = 0; mi < 4; ++mi) {
                int row = wr * 64 + mi * 16 + l15;
                af[mi] = *(const bf16x8*)(Ab + row * 128 +
                                          ((((kk >> 3) + lg) ^ (row & 7)) << 4));
            }
#pragma unroll
            for (int ni = 0; ni < 4; ++ni) {
                int row = wc * 64 + ni * 16 + l15;
                bfv[ni] = *(const bf16x8*)(Bb + 128 * row +
                                           ((((kk >> 3) + lg) ^ (row & 7)) << 4));
            }
            __builtin_amdgcn_s_setprio(1);
#pragma unroll
            for (int mi = 0; mi < 4; ++mi)
#pragma unroll
                for (int ni = 0; ni < 4; ++ni)
                    acc[mi][ni] = MFMA_BF16(af[mi], bfv[ni], acc[mi][ni]);
            __builtin_amdgcn_s_setprio(0);
        }
        if (ks + 1 < CD / 64) AWRITE(cur ^ 1);  // write-late: loads landed under compute
        __syncthreads();  // drains glds (covered) + A ds_writes; orders buffer reuse
    }

    if (z == 2) {
        // xvT: (m,n) -> C2[n*CM + (m&~63) | cp(m&63)]
        bf16* C = p.C2;
        const int mblock = m0 + wr * 64;
#pragma unroll
        for (int ni = 0; ni < 4; ++ni) {
            int n = n0 + wc * 64 + ni * 16 + l15;
            float bv = bias[n];
#pragma unroll
            for (int mi = 0; mi < 4; ++mi) {
                int s = mi * 16 + lg * 4;  // s&3 == 0
                int cps = (s & 32) | ((s & 12) << 1) | ((s & 16) >> 2);
                bf16x4 o;
#pragma unroll
                for (int r = 0; r < 4; ++r) o[r] = (bf16)(acc[mi][ni][r] + bv);
                *(bf16x4*)(C + (size_t)n * CM + mblock + cps) = o;
            }
        }
    } else {
        bf16* C = (z == 0) ? p.C0 : p.C1;
#pragma unroll
        for (int ni = 0; ni < 4; ++ni) {
            int col = n0 + wc * 64 + ni * 16 + l15;
            float bv = bias[col];
#pragma unroll
            for (int mi = 0; mi < 4; ++mi)
#pragma unroll
                for (int r = 0; r < 4; ++r) {
                    int row = m0 + wr * 64 + mi * 16 + lg * 4 + r;
                    C[(size_t)row * CDA + col] = (bf16)(acc[mi][ni][r] + bv);
                }
        }
    }
}

// ---------------------------------------------------------------------------
// Output projection: same 1-barrier pipelined loop; A and B both glds-dbuf.
// ---------------------------------------------------------------------------
__global__ __launch_bounds__(512, 2) void gemm_out(
    const bf16* __restrict__ A, const bf16* __restrict__ W,
    const float* __restrict__ bias, float* __restrict__ C)
{
    __shared__ __align__(16) char smem[98304];  // A: 2x16K @0, B: 2x32K @32768

    const int t = threadIdx.x;
    const int lane = t & 63;
    const int wid = t >> 6;
    const int wr = wid >> 2, wc = wid & 3;
    const int l15 = lane & 15, lg = lane >> 4;
    const int m0 = blockIdx.x * 128;
    const int n0 = blockIdx.y * 256;

    const int grow_ = wid * 8 + (lane >> 3);
    const int gcol = ((lane & 7) ^ ((lane >> 3) & 7)) << 3;

    auto STAGE = [&](int bufi, int k0) {
        char* Ab = smem + bufi * 16384;
        char* Bb = smem + 32768 + bufi * 32768;
#pragma unroll
        for (int i = 0; i < 2; ++i) {
            const bf16* src = A + (size_t)(m0 + i * 64 + grow_) * CDA + k0 + gcol;
            __builtin_amdgcn_global_load_lds(
                (const __attribute__((address_space(1))) void*)src,
                (__attribute__((address_space(3))) void*)(Ab + i * 8192 + wid * 1024),
                16, 0, 0);
        }
#pragma unroll
        for (int i = 0; i < 4; ++i) {
            const bf16* src = W + (size_t)(n0 + i * 64 + grow_) * CDA + k0 + gcol;
            __builtin_amdgcn_global_load_lds(
                (const __attribute__((address_space(1))) void*)src,
                (__attribute__((address_space(3))) void*)(Bb + i * 8192 + wid * 1024),
                16, 0, 0);
        }
    };

    f32x4 acc[4][4] = {};

    STAGE(0, 0);
    __syncthreads();

    for (int ks = 0; ks < CDA / 64; ++ks) {
        const int cur = ks & 1;
        if (ks + 1 < CDA / 64) STAGE(cur ^ 1, (ks + 1) * 64);
        char* Ab = smem + cur * 16384;
        char* Bb = smem + 32768 + cur * 32768;
#pragma unroll
        for (int kk = 0; kk < 64; kk += 32) {
            bf16x8 af[4], bfv[4];
#pragma unroll
            for (int mi = 0; mi < 4; ++mi) {
                int row = wr * 64 + mi * 16 + l15;
                af[mi] = *(const bf16x8*)(Ab + row * 128 +
                                          ((((kk >> 3) + lg) ^ (row & 7)) << 4));
            }
#pragma unroll
            for (int ni = 0; ni < 4; ++ni) {
                int row = wc * 64 + ni * 16 + l15;
                bfv[ni] = *(const bf16x8*)(Bb + 128 * row +
                                           ((((kk >> 3) + lg) ^ (row & 7)) << 4));
            }
            __builtin_amdgcn_s_setprio(1);
#pragma unroll
            for (int mi = 0; mi < 4; ++mi)
#pragma unroll
                for (int ni = 0; ni < 4; ++ni)
                    acc[mi][ni] = MFMA_BF16(af[mi], bfv[ni], acc[mi][ni]);
            __builtin_amdgcn_s_setprio(0);
        }
        __syncthreads();  // drains next-tile glds (covered by compute); buffer reuse
    }

#pragma unroll
    for (int ni = 0; ni < 4; ++ni) {
        int col = n0 + wc * 64 + ni * 16 + l15;
        float bv = bias[col];
#pragma unroll
        for (int mi = 0; mi < 4; ++mi)
#pragma unroll
            for (int r = 0; r < 4; ++r) {
                int row = m0 + wr * 64 + mi * 16 + lg * 4 + r;
                C[(size_t)row * CD + col] = acc[mi][ni][r] + bv;
            }
    }
}

// ---------------------------------------------------------------------------
// Flash attention — best-known version (2-buffer glds, __syncthreads drain).
// 512 threads = 8 waves, 256 q-rows/block, XCD-swizzled grid of 512.
// ---------------------------------------------------------------------------
__global__ __launch_bounds__(512, 4) void attn_kernel(
    const bf16* __restrict__ xq, const bf16* __restrict__ xk,
    const bf16* __restrict__ xvT, const int* __restrict__ mask,
    bf16* __restrict__ out)
{
    __shared__ __align__(16) char smem[40960];
    float* Mb = (float*)(smem + 32768);        // per-block mask bias, f32[2048]

    const int t = threadIdx.x;
    const int lane = t & 63;
    const int wid = t >> 6;                    // 0..7
    const int l15 = lane & 15, lg = lane >> 4;
    const int g = blockIdx.x;
    const int j = g >> 3;
    const int bh = (g & 7) * 8 + (j & 7);
    const int qt = j >> 3;
    const int b = bh >> 4, h = bh & 15;
    const int q0 = qt * 256;
    constexpr float SCL = 0.125f * 1.44269504088896340736f;
    constexpr float M2 = 12.0f * SCL;

    const int sub = lane >> 3;
    const int sb  = (lane & 7) ^ sub;
    const bf16* kbase = xk + (size_t)(b * CS + wid * 8 + sub) * CDA + h * 64 + sb * 8;
    const bf16* vbase = xvT + (size_t)(h * 64 + wid * 8 + sub) * CM + b * CS + sb * 8;

#define STAGE(bufi, ktt)                                                           \
    {                                                                              \
        char* Kd = smem + (bufi) * 16384 + wid * 1024;                             \
        char* Vd = smem + (bufi) * 16384 + 8192 + wid * 1024;                      \
        __builtin_amdgcn_global_load_lds(                                          \
            (const __attribute__((address_space(1))) void*)(kbase + (size_t)(ktt) * 64 * CDA), \
            (__attribute__((address_space(3))) void*)Kd, 16, 0, 0);                \
        __builtin_amdgcn_global_load_lds(                                          \
            (const __attribute__((address_space(1))) void*)(vbase + (ktt) * 64),   \
            (__attribute__((address_space(3))) void*)Vd, 16, 0, 0);                \
    }

    {
        i32x4 mk = *(const i32x4*)(mask + b * CS + t * 4);
        f32x4 o;
#pragma unroll
        for (int r = 0; r < 4; ++r) o[r] = (mk[r] == 0) ? -1.0e30f : -M2;
        *(f32x4*)(Mb + t * 4) = o;
    }

    bf16x8 aq[2][2];
#pragma unroll
    for (int mi = 0; mi < 2; ++mi)
#pragma unroll
        for (int kh = 0; kh < 2; ++kh) {
            bf16x8 v = *(const bf16x8*)(xq +
                (size_t)(b * CS + q0 + wid * 32 + mi * 16 + l15) * CDA + h * 64 + kh * 32 + lg * 8);
#pragma unroll
            for (int jj = 0; jj < 8; ++jj) v[jj] = (bf16)((float)v[jj] * SCL);
            aq[mi][kh] = v;
        }

    bf16x8 onescol;
    {
        bf16 fv = (l15 == 0) ? (bf16)1.0f : (bf16)0.0f;
#pragma unroll
        for (int jj = 0; jj < 8; ++jj) onescol[jj] = fv;
    }

    int koff[2][4], voff[2][4];
#pragma unroll
    for (int kh = 0; kh < 2; ++kh)
#pragma unroll
        for (int ni = 0; ni < 4; ++ni) {
            int key = ni * 16 + l15;
            koff[kh][ni] = key * 128 + ((kh * 64 + lg * 16) ^ ((key & 7) << 4));
        }
#pragma unroll
    for (int kks = 0; kks < 2; ++kks)
#pragma unroll
        for (int di = 0; di < 4; ++di) {
            int d = di * 16 + l15;
            voff[kks][di] = 8192 + d * 128 + ((kks * 64 + lg * 16) ^ ((d & 7) << 4));
        }

    f32x4 accO[2][5] = {};

    STAGE(0, 0);
    __syncthreads();

    for (int kt = 0; kt < NT; ++kt) {
        const int cur = kt & 1;
        char* buf = smem + cur * 16384;

        if (kt + 1 < NT) STAGE(cur ^ 1, kt + 1);

        f32x4 mb[4];
#pragma unroll
        for (int ni = 0; ni < 4; ++ni)
            mb[ni] = *(const f32x4*)(Mb + kt * 64 + ni * 16 + lg * 4);

        f32x4 sT[4][2];
#pragma unroll
        for (int ni = 0; ni < 4; ++ni) { sT[ni][0] = mb[ni]; sT[ni][1] = mb[ni]; }
#pragma unroll
        for (int kh = 0; kh < 2; ++kh) {
            bf16x8 bk[4];
#pragma unroll
            for (int ni = 0; ni < 4; ++ni)
                bk[ni] = *(const bf16x8*)(buf + koff[kh][ni]);
            __builtin_amdgcn_s_setprio(1);
#pragma unroll
            for (int ni = 0; ni < 4; ++ni)
#pragma unroll
                for (int mi = 0; mi < 2; ++mi)
                    sT[ni][mi] = MFMA_BF16(bk[ni], aq[mi][kh], sT[ni][mi]);
            __builtin_amdgcn_s_setprio(0);
        }

#pragma unroll
        for (int ni = 0; ni < 4; ++ni)
#pragma unroll
            for (int mi = 0; mi < 2; ++mi)
#pragma unroll
                for (int r = 0; r < 4; ++r)
                    sT[ni][mi][r] = exp2f(sT[ni][mi][r]);

        bf16x8 ap[2][2];
#pragma unroll
        for (int kks = 0; kks < 2; ++kks)
#pragma unroll
            for (int mi = 0; mi < 2; ++mi)
#pragma unroll
                for (int r = 0; r < 4; ++r) {
                    ap[kks][mi][r]     = (bf16)sT[2 * kks][mi][r];
                    ap[kks][mi][4 + r] = (bf16)sT[2 * kks + 1][mi][r];
                }

#pragma unroll
        for (int kks = 0; kks < 2; ++kks) {
            bf16x8 bv[4];
#pragma unroll
            for (int di = 0; di < 4; ++di)
                bv[di] = *(const bf16x8*)(buf + voff[kks][di]);
            __builtin_amdgcn_s_setprio(1);
#pragma unroll
            for (int mi = 0; mi < 2; ++mi) {
#pragma unroll
                for (int di = 0; di < 4; ++di)
                    accO[mi][di] = MFMA_BF16(ap[kks][mi], bv[di], accO[mi][di]);
                accO[mi][4] = MFMA_BF16(ap[kks][mi], onescol, accO[mi][4]);
            }
            __builtin_amdgcn_s_setprio(0);
        }

        __syncthreads();
    }
#undef STAGE

    char* Ob = smem + wid * 2048;
#pragma unroll
    for (int mi = 0; mi < 2; ++mi) {
#pragma unroll
        for (int r = 0; r < 4; ++r) {
            float lsum = __shfl(accO[mi][4][r], lane & 48);
            float inv = 1.0f / lsum;
            int qr = lg * 4 + r;
#pragma unroll
            for (int di = 0; di < 4; ++di)
                *(bf16*)(Ob + qr * 128 + (((di * 16 + l15) * 2) ^ ((qr & 7) << 4))) =
                    (bf16)(accO[mi][di][r] * inv);
        }
        __builtin_amdgcn_sched_barrier(0);
#pragma unroll
        for (int i = 0; i < 2; ++i) {
            int rr = i * 8 + (lane >> 3);
            int ch = lane & 7;
            bf16x8 o = *(const bf16x8*)(Ob + rr * 128 + ((ch * 16) ^ ((rr & 7) << 4)));
            *(bf16x8*)(out + (size_t)(b * CS + q0 + wid * 32 + mi * 16 + rr) * CDA +
                       h * 64 + ch * 8) = o;
        }
        __builtin_amdgcn_sched_barrier(0);
    }
}

// ---------------------------------------------------------------------------
extern "C" void kernel_launch(void* const* d_in, const int* in_sizes, int n_in,
                              void* d_out, int out_size, void* d_ws, size_t ws_size,
                              hipStream_t stream)
{
    const float* q   = (const float*)d_in[0];
    const float* k   = (const float*)d_in[1];
    const float* v   = (const float*)d_in[2];
    const int*   msk = (const int*)d_in[3];
    const float* w_q = (const float*)d_in[4];
    const float* b_q = (const float*)d_in[5];
    const float* w_k = (const float*)d_in[6];
    const float* b_k = (const float*)d_in[7];
    const float* w_v = (const float*)d_in[8];
    const float* b_v = (const float*)d_in[9];
    const float* w_o = (const float*)d_in[10];
    const float* b_o = (const float*)d_in[11];

    bf16* xq  = (bf16*)d_ws;
    bf16* xk  = xq + (size_t)CM * CDA;
    bf16* xvT = xk + (size_t)CM * CDA;   // [DA][CM], keys permuted within 64-blocks
    bf16* at  = xvT + (size_t)CM * CDA;
    bf16* wb  = at + (size_t)CM * CDA;   // 4 x 1M bf16 weights (q,k,v,o)

    cvt_w4<<<dim3(2048), 256, 0, stream>>>(w_q, w_k, w_v, w_o, wb);

    P3 p{q, k, v, b_q, b_k, b_v, xq, xk, xvT};
    gemm_proj<<<dim3(CM / 128, CDA / 256, 3), 512, 0, stream>>>(p, wb);

    attn_kernel<<<dim3(512), 512, 0, stream>>>(xq, xk, xvT, msk, at);

    gemm_out<<<dim3(CM / 128, CD / 256), 512, 0, stream>>>(
        at, wb + 3 * (size_t)(CD * CDA), b_o, (float*)d_out);
}